// Round 10
// baseline (259.242 us; speedup 1.0000x reference)
//
#include <hip/hip_runtime.h>
#include <math.h>

#define N_NODES 50000
#define N_EDGES 800000
#define IN_F 256
#define OUT_F 128
#define RANK 64
#define NCOMB 192  // OUT_F + RANK
#define REC 192    // ushorts per node record (128 sum + 64 prod) = 384 B
#define NB_SCAN ((N_NODES + 255) / 256)  // 196
#define NB_GEMM ((N_NODES + 63) / 64)    // 782
#define NQ 3125                          // agg blocks per quarter (12500/4)

typedef unsigned int uint;
typedef unsigned short ushort;
using f32x4 = __attribute__((ext_vector_type(4))) float;
typedef __attribute__((ext_vector_type(8))) short short8;

__device__ __forceinline__ ushort f2bf(float x) {
    uint u = __float_as_uint(x);
    uint r = (u + 0x7fffu + ((u >> 16) & 1u)) >> 16;
    return (ushort)r;
}
__device__ __forceinline__ float bflo(uint u) { return __uint_as_float(u << 16); }
__device__ __forceinline__ float bfhi(uint u) { return __uint_as_float(u & 0xffff0000u); }
__device__ __forceinline__ uint pack2(float lo, float hi) {
    return (uint)f2bf(lo) | ((uint)f2bf(hi) << 16);
}

// ------- fused weight-prep + degree count (rank trick) -------
__global__ __launch_bounds__(256) void k_prepdeg(const float* __restrict__ w1,
                                                 const float* __restrict__ w2,
                                                 const int* __restrict__ src,
                                                 const int* __restrict__ dst,
                                                 ushort* __restrict__ BtG,
                                                 float* __restrict__ bias,
                                                 int* __restrict__ out_deg,
                                                 int* __restrict__ in_deg,
                                                 ushort* __restrict__ rank) {
    int g = blockIdx.x * 256 + threadIdx.x;
    if (g < NCOMB * IN_F) {
        int n = g >> 8;
        int k = g & 255;
        float v = (n < OUT_F) ? w1[k * OUT_F + n] : w2[k * RANK + (n - OUT_F)];
        BtG[n * IN_F + k] = f2bf(v);
    }
    if (g < RANK) bias[g] = w2[IN_F * RANK + g];
    int base = g * 4;
    if (base < N_EDGES) {
        int4 s4 = *(const int4*)(src + base);
        int4 d4 = *(const int4*)(dst + base);
        atomicAdd(&out_deg[s4.x], 1);
        atomicAdd(&out_deg[s4.y], 1);
        atomicAdd(&out_deg[s4.z], 1);
        atomicAdd(&out_deg[s4.w], 1);
        rank[base + 0] = (ushort)atomicAdd(&in_deg[d4.x], 1);
        rank[base + 1] = (ushort)atomicAdd(&in_deg[d4.y], 1);
        rank[base + 2] = (ushort)atomicAdd(&in_deg[d4.z], 1);
        rank[base + 3] = (ushort)atomicAdd(&in_deg[d4.w], 1);
    }
}

// ------- scan phase 1: per-block sums -------
__global__ __launch_bounds__(256) void k_bsum(const int* __restrict__ in_deg,
                                              int* __restrict__ bsum) {
    __shared__ int red[4];
    int t = threadIdx.x;
    int idx = blockIdx.x * 256 + t;
    int v = (idx < N_NODES) ? in_deg[idx] : 0;
#pragma unroll
    for (int m = 1; m < 64; m <<= 1) v += __shfl_xor(v, m, 64);
    if ((t & 63) == 0) red[t >> 6] = v;
    __syncthreads();
    if (t == 0) bsum[blockIdx.x] = red[0] + red[1] + red[2] + red[3];
}

// ------- scan phase 2: tiny bsum scan + local scan -------
__global__ __launch_bounds__(256) void k_scat2(const int* __restrict__ in_deg,
                                               const int* __restrict__ bsum,
                                               int* __restrict__ row_start) {
    __shared__ int s[256];
    int t = threadIdx.x;
    int b = blockIdx.x;
    int bv = (t < NB_SCAN) ? bsum[t] : 0;
    s[t] = bv;
    __syncthreads();
    for (int st = 1; st < 256; st <<= 1) {
        int x = 0;
        if (t >= st) x = s[t - st];
        __syncthreads();
        if (t >= st) s[t] += x;
        __syncthreads();
    }
    int off = (b > 0) ? s[b - 1] : 0;
    __syncthreads();
    int idx = b * 256 + t;
    int v = (idx < N_NODES) ? in_deg[idx] : 0;
    s[t] = v;
    __syncthreads();
    for (int st = 1; st < 256; st <<= 1) {
        int x = 0;
        if (t >= st) x = s[t - st];
        __syncthreads();
        if (t >= st) s[t] += x;
        __syncthreads();
    }
    if (idx < N_NODES) row_start[idx] = off + s[t] - v;
    if (b == NB_SCAN - 1 && t == 0) row_start[N_NODES] = N_EDGES;
}

// ------- fused MFMA node GEMM + atomic-free CSR fill (1:1 interleave) -----
#define BM 64
#define BK 64
__global__ __launch_bounds__(256) void k_gemmfill(
    const float* __restrict__ feat,
    const ushort* __restrict__ BtG,
    const float* __restrict__ bias,
    const int* __restrict__ out_deg,
    const int* __restrict__ src,
    const int* __restrict__ dst,
    const ushort* __restrict__ rank,
    const int* __restrict__ row_start,
    int* __restrict__ csr_src,
    ushort* __restrict__ feat_rec) {
    __shared__ __align__(16) ushort A_l[BM * BK];
    __shared__ __align__(16) ushort B_l[NCOMB * BK];
    int bid = blockIdx.x;
    int tid = threadIdx.x;

    if (bid & 1) {
        // fill block: 1024 edges, vectorized index reads, no atomics
        int base = (bid >> 1) * 1024 + tid * 4;
        if (base < N_EDGES) {
            int4 s4 = *(const int4*)(src + base);
            int4 d4 = *(const int4*)(dst + base);
            uint2 rq = *(const uint2*)(rank + base);
            csr_src[row_start[d4.x] + (int)(rq.x & 0xffff)] = s4.x;
            csr_src[row_start[d4.y] + (int)(rq.x >> 16)] = s4.y;
            csr_src[row_start[d4.z] + (int)(rq.y & 0xffff)] = s4.z;
            csr_src[row_start[d4.w] + (int)(rq.y >> 16)] = s4.w;
        }
        return;
    }

    int gid = bid >> 1;
    int wid = tid >> 6, lane = tid & 63;
    int n0 = gid * BM;

    f32x4 acc[12];
#pragma unroll
    for (int t = 0; t < 12; ++t) acc[t] = (f32x4)(0.f);

    int ar = tid >> 2;
    int ac = (tid & 3) << 4;
    const float* arow = feat + (size_t)(n0 + ar) * IN_F + ac;
    bool arow_ok = (n0 + ar) < N_NODES;

    float4 v0, v1, v2, v3;
    uint4 bg0, bg1, bg2, bg3, bg4, bg5;

#define LOADA(KT)                                                     \
    do {                                                              \
        if (arow_ok) {                                                \
            const float4* p = (const float4*)(arow + (KT) * BK);      \
            v0 = p[0]; v1 = p[1]; v2 = p[2]; v3 = p[3];               \
        } else {                                                      \
            v0 = v1 = v2 = v3 = make_float4(0.f, 0.f, 0.f, 0.f);     \
        }                                                             \
    } while (0)

#define LOADB1(II, DEST)                                              \
    do {                                                              \
        int cc = tid + 256 * (II);                                    \
        int row = cc >> 3;                                            \
        int cb = (cc & 7) << 4;                                       \
        DEST = *(const uint4*)((const char*)BtG + row * 512 + ktn * 128 + cb); \
    } while (0)

    {
        int ktn = 0;
        LOADA(0);
        LOADB1(0, bg0); LOADB1(1, bg1); LOADB1(2, bg2);
        LOADB1(3, bg3); LOADB1(4, bg4); LOADB1(5, bg5);
    }

    for (int kt = 0; kt < 4; ++kt) {
        {
            uint4 w0 = make_uint4(pack2(v0.x, v0.y), pack2(v0.z, v0.w),
                                  pack2(v1.x, v1.y), pack2(v1.z, v1.w));
            uint4 w1q = make_uint4(pack2(v2.x, v2.y), pack2(v2.z, v2.w),
                                   pack2(v3.x, v3.y), pack2(v3.z, v3.w));
            int base = ar * 128 + ac * 2;
            int swz = (ar & 7) << 4;
            *(uint4*)((char*)A_l + (base ^ swz)) = w0;
            *(uint4*)((char*)A_l + ((base + 16) ^ swz)) = w1q;
        }
        {
            uint4 bgs[6] = {bg0, bg1, bg2, bg3, bg4, bg5};
#pragma unroll
            for (int ii = 0; ii < 6; ++ii) {
                int cc = tid + 256 * ii;
                int row = cc >> 3;
                int cb = (cc & 7) << 4;
                int b = (row * 128 + cb) ^ ((row & 7) << 4);
                *(uint4*)((char*)B_l + b) = bgs[ii];
            }
        }
        __syncthreads();
        if (kt < 3) {
            int ktn = kt + 1;
            LOADA(ktn);
            LOADB1(0, bg0); LOADB1(1, bg1); LOADB1(2, bg2);
            LOADB1(3, bg3); LOADB1(4, bg4); LOADB1(5, bg5);
        }
        {
            int arow_f = wid * 16 + (lane & 15);
            int kchunk = lane >> 4;
            int aswz = (arow_f & 7) << 4;
#pragma unroll
            for (int s = 0; s < 2; ++s) {
                int abyte = (arow_f * 128 + s * 64 + kchunk * 16) ^ aswz;
                short8 afrag = *(const short8*)((const char*)A_l + abyte);
#pragma unroll
                for (int t = 0; t < 12; ++t) {
                    int brow = t * 16 + (lane & 15);
                    int bbyte = (brow * 128 + s * 64 + kchunk * 16) ^ ((brow & 7) << 4);
                    short8 bfrag = *(const short8*)((const char*)B_l + bbyte);
                    acc[t] = __builtin_amdgcn_mfma_f32_16x16x32_bf16(afrag, bfrag,
                                                                     acc[t], 0, 0, 0);
                }
            }
        }
        __syncthreads();
    }

    int col = lane & 15;
    int r0 = wid * 16 + ((lane >> 4) << 2);
#pragma unroll
    for (int q = 0; q < 4; ++q) {
        int n = n0 + r0 + q;
        if (n < N_NODES) {
            float s = rsqrtf(fmaxf((float)out_deg[n], 1.f));
            ushort* rec = feat_rec + (size_t)n * REC;
#pragma unroll
            for (int t = 0; t < 8; ++t)
                rec[t * 16 + col] = f2bf(acc[t][q] * s);
#pragma unroll
            for (int t = 8; t < 12; ++t) {
                float z = acc[t][q] * s + bias[(t - 8) * 16 + col];
                rec[OUT_F + (t - 8) * 16 + col] = f2bf(tanhf(z));
            }
        }
    }
}

// ---------------- aggregation quarter: unified 384-B record gather -------
__global__ __launch_bounds__(256) void k_agg(const ushort* __restrict__ feat_rec,
                                             const int* __restrict__ row_start,
                                             const int* __restrict__ csr_src,
                                             const int* __restrict__ in_deg,
                                             const float* __restrict__ vmat,
                                             float* __restrict__ out,
                                             int q0) {
    __shared__ float sum_s[4][OUT_F];
    __shared__ float prod_s[4][RANK];
    int wid = threadIdx.x >> 6;
    int lane = threadIdx.x & 63;
    int g = lane >> 4;
    int i = lane & 15;
    int d = (q0 + blockIdx.x) * 4 + wid;

    int beg = row_start[d];
    int end = row_start[d + 1];
    int deg = end - beg;

    const char* frb = (const char*)feat_rec;  // record stride 384 B

    float a0 = 0.f, a1 = 0.f, a2 = 0.f, a3 = 0.f;
    float a4 = 0.f, a5 = 0.f, a6 = 0.f, a7 = 0.f;
    float p0 = 1.f, p1 = 1.f, p2 = 1.f, p3 = 1.f;

    if (deg > 0) {
        int cl = end - 1;
        int e0 = beg + g * 4;
        int sA = csr_src[min(e0 + 0, cl)];
        int sB = csr_src[min(e0 + 1, cl)];
        int sC = csr_src[min(e0 + 2, cl)];
        int sD = csr_src[min(e0 + 3, cl)];
        int niter = (deg + 15) >> 4;
        for (int it = 0; it < niter; ++it) {
            size_t bA = (size_t)sA * 384, bB = (size_t)sB * 384;
            size_t bC = (size_t)sC * 384, bD = (size_t)sD * 384;
            uint4 uA = *(const uint4*)(frb + bA + (i << 4));
            uint4 uB = *(const uint4*)(frb + bB + (i << 4));
            uint4 uC = *(const uint4*)(frb + bC + (i << 4));
            uint4 uD = *(const uint4*)(frb + bD + (i << 4));
            uint2 qA = *(const uint2*)(frb + bA + 256 + (i << 3));
            uint2 qB = *(const uint2*)(frb + bB + 256 + (i << 3));
            uint2 qC = *(const uint2*)(frb + bC + 256 + (i << 3));
            uint2 qD = *(const uint2*)(frb + bD + 256 + (i << 3));
            bool vA = (e0 + 0) < end;
            bool vB = (e0 + 1) < end;
            bool vC = (e0 + 2) < end;
            bool vD = (e0 + 3) < end;
            float mA = vA ? 1.f : 0.f;
            float mB = vB ? 1.f : 0.f;
            float mC = vC ? 1.f : 0.f;
            float mD = vD ? 1.f : 0.f;
            e0 += 16;
            sA = csr_src[min(e0 + 0, cl)];
            sB = csr_src[min(e0 + 1, cl)];
            sC = csr_src[min(e0 + 2, cl)];
            sD = csr_src[min(e0 + 3, cl)];
            a0 = fmaf(mA, bflo(uA.x), a0); a1 = fmaf(mA, bfhi(uA.x), a1);
            a2 = fmaf(mA, bflo(uA.y), a2); a3 = fmaf(mA, bfhi(uA.y), a3);
            a4 = fmaf(mA, bflo(uA.z), a4); a5 = fmaf(mA, bfhi(uA.z), a5);
            a6 = fmaf(mA, bflo(uA.w), a6); a7 = fmaf(mA, bfhi(uA.w), a7);
            a0 = fmaf(mB, bflo(uB.x), a0); a1 = fmaf(mB, bfhi(uB.x), a1);
            a2 = fmaf(mB, bflo(uB.y), a2); a3 = fmaf(mB, bfhi(uB.y), a3);
            a4 = fmaf(mB, bflo(uB.z), a4); a5 = fmaf(mB, bfhi(uB.z), a5);
            a6 = fmaf(mB, bflo(uB.w), a6); a7 = fmaf(mB, bfhi(uB.w), a7);
            a0 = fmaf(mC, bflo(uC.x), a0); a1 = fmaf(mC, bfhi(uC.x), a1);
            a2 = fmaf(mC, bflo(uC.y), a2); a3 = fmaf(mC, bfhi(uC.y), a3);
            a4 = fmaf(mC, bflo(uC.z), a4); a5 = fmaf(mC, bfhi(uC.z), a5);
            a6 = fmaf(mC, bflo(uC.w), a6); a7 = fmaf(mC, bfhi(uC.w), a7);
            a0 = fmaf(mD, bflo(uD.x), a0); a1 = fmaf(mD, bfhi(uD.x), a1);
            a2 = fmaf(mD, bflo(uD.y), a2); a3 = fmaf(mD, bfhi(uD.y), a3);
            a4 = fmaf(mD, bflo(uD.z), a4); a5 = fmaf(mD, bfhi(uD.z), a5);
            a6 = fmaf(mD, bflo(uD.w), a6); a7 = fmaf(mD, bfhi(uD.w), a7);
            p0 *= vA ? bflo(qA.x) : 1.f; p1 *= vA ? bfhi(qA.x) : 1.f;
            p2 *= vA ? bflo(qA.y) : 1.f; p3 *= vA ? bfhi(qA.y) : 1.f;
            p0 *= vB ? bflo(qB.x) : 1.f; p1 *= vB ? bfhi(qB.x) : 1.f;
            p2 *= vB ? bflo(qB.y) : 1.f; p3 *= vB ? bfhi(qB.y) : 1.f;
            p0 *= vC ? bflo(qC.x) : 1.f; p1 *= vC ? bfhi(qC.x) : 1.f;
            p2 *= vC ? bflo(qC.y) : 1.f; p3 *= vC ? bfhi(qC.y) : 1.f;
            p0 *= vD ? bflo(qD.x) : 1.f; p1 *= vD ? bfhi(qD.x) : 1.f;
            p2 *= vD ? bflo(qD.y) : 1.f; p3 *= vD ? bfhi(qD.y) : 1.f;
        }
    }

    a0 += __shfl_xor(a0, 16, 64); a0 += __shfl_xor(a0, 32, 64);
    a1 += __shfl_xor(a1, 16, 64); a1 += __shfl_xor(a1, 32, 64);
    a2 += __shfl_xor(a2, 16, 64); a2 += __shfl_xor(a2, 32, 64);
    a3 += __shfl_xor(a3, 16, 64); a3 += __shfl_xor(a3, 32, 64);
    a4 += __shfl_xor(a4, 16, 64); a4 += __shfl_xor(a4, 32, 64);
    a5 += __shfl_xor(a5, 16, 64); a5 += __shfl_xor(a5, 32, 64);
    a6 += __shfl_xor(a6, 16, 64); a6 += __shfl_xor(a6, 32, 64);
    a7 += __shfl_xor(a7, 16, 64); a7 += __shfl_xor(a7, 32, 64);
    p0 *= __shfl_xor(p0, 16, 64); p0 *= __shfl_xor(p0, 32, 64);
    p1 *= __shfl_xor(p1, 16, 64); p1 *= __shfl_xor(p1, 32, 64);
    p2 *= __shfl_xor(p2, 16, 64); p2 *= __shfl_xor(p2, 32, 64);
    p3 *= __shfl_xor(p3, 16, 64); p3 *= __shfl_xor(p3, 32, 64);

    if (g == 0) {
        sum_s[wid][i * 8 + 0] = a0; sum_s[wid][i * 8 + 1] = a1;
        sum_s[wid][i * 8 + 2] = a2; sum_s[wid][i * 8 + 3] = a3;
        sum_s[wid][i * 8 + 4] = a4; sum_s[wid][i * 8 + 5] = a5;
        sum_s[wid][i * 8 + 6] = a6; sum_s[wid][i * 8 + 7] = a7;
        prod_s[wid][i * 4 + 0] = p0; prod_s[wid][i * 4 + 1] = p1;
        prod_s[wid][i * 4 + 2] = p2; prod_s[wid][i * 4 + 3] = p3;
    }

    float o0 = sum_s[wid][lane * 2];
    float o1 = sum_s[wid][lane * 2 + 1];
    if (deg > 0) {
#pragma unroll 8
        for (int r = 0; r < RANK; ++r) {
            float p = prod_s[wid][r];
            float2 v2 = *(const float2*)(vmat + r * OUT_F + lane * 2);
            o0 += p * v2.x;
            o1 += p * v2.y;
        }
    }
    float sc = rsqrtf(fmaxf((float)in_deg[d], 1.f));
    float2 res;
    res.x = o0 * sc;
    res.y = o1 * sc;
    *(float2*)(out + (size_t)d * OUT_F + lane * 2) = res;
}

extern "C" void kernel_launch(void* const* d_in, const int* in_sizes, int n_in,
                              void* d_out, int out_size, void* d_ws, size_t ws_size,
                              hipStream_t stream) {
    const float* feat = (const float*)d_in[0];
    const float* w1   = (const float*)d_in[1];
    const float* w2   = (const float*)d_in[2];
    const float* vmat = (const float*)d_in[3];
    const int*   src  = (const int*)d_in[4];
    const int*   dst  = (const int*)d_in[5];
    float* out = (float*)d_out;

    char* ws = (char*)d_ws;
    size_t off = 0;
    auto alloc = [&](size_t bytes) {
        void* p = ws + off;
        off = (off + bytes + 255) & ~(size_t)255;
        return p;
    };
    int* degs      = (int*)alloc(2 * N_NODES * sizeof(int));  // out_deg | in_deg
    int* out_deg   = degs;
    int* in_deg    = degs + N_NODES;
    int* row_start = (int*)alloc((N_NODES + 1) * sizeof(int));
    int* csr_src   = (int*)alloc(N_EDGES * sizeof(int));
    int* bsum      = (int*)alloc(NB_SCAN * sizeof(int));
    ushort* rank   = (ushort*)alloc(N_EDGES * sizeof(ushort));
    ushort* feat_rec = (ushort*)alloc((size_t)N_NODES * REC * sizeof(ushort));
    ushort* BtG      = (ushort*)alloc((size_t)NCOMB * IN_F * sizeof(ushort));
    float*  bias     = (float*)alloc(RANK * sizeof(float));

    hipMemsetAsync(degs, 0, 2 * N_NODES * sizeof(int), stream);

    k_prepdeg<<<(N_EDGES / 4 + 255) / 256, 256, 0, stream>>>(w1, w2, src, dst,
                                                             BtG, bias, out_deg,
                                                             in_deg, rank);
    k_bsum<<<NB_SCAN, 256, 0, stream>>>(in_deg, bsum);
    k_scat2<<<NB_SCAN, 256, 0, stream>>>(in_deg, bsum, row_start);
    k_gemmfill<<<NB_GEMM * 2, 256, 0, stream>>>(feat, BtG, bias, out_deg,
                                                src, dst, rank, row_start,
                                                csr_src, feat_rec);
    k_agg<<<NQ, 256, 0, stream>>>(feat_rec, row_start, csr_src, in_deg, vmat, out, 0);
    k_agg<<<NQ, 256, 0, stream>>>(feat_rec, row_start, csr_src, in_deg, vmat, out, NQ);
    k_agg<<<NQ, 256, 0, stream>>>(feat_rec, row_start, csr_src, in_deg, vmat, out, 2 * NQ);
    k_agg<<<NQ, 256, 0, stream>>>(feat_rec, row_start, csr_src, in_deg, vmat, out, 3 * NQ);
}

// Round 11
// 237.651 us; speedup vs baseline: 1.0909x; 1.0909x over previous
//
#include <hip/hip_runtime.h>
#include <math.h>

#define N_NODES 50000
#define N_EDGES 800000
#define IN_F 256
#define OUT_F 128
#define RANK 64
#define NCOMB 192  // OUT_F + RANK
#define REC 192    // ushorts per node record (128 sum + 64 prod) = 384 B
#define NB_SCAN ((N_NODES + 255) / 256)  // 196
#define NB_GEMM ((N_NODES + 63) / 64)    // 782
#define DPAD 8     // ints per degree counter (32-B sector each)

typedef unsigned int uint;
typedef unsigned short ushort;
using f32x4 = __attribute__((ext_vector_type(4))) float;
typedef __attribute__((ext_vector_type(8))) short short8;

__device__ __forceinline__ ushort f2bf(float x) {
    uint u = __float_as_uint(x);
    uint r = (u + 0x7fffu + ((u >> 16) & 1u)) >> 16;
    return (ushort)r;
}
__device__ __forceinline__ float bflo(uint u) { return __uint_as_float(u << 16); }
__device__ __forceinline__ float bfhi(uint u) { return __uint_as_float(u & 0xffff0000u); }
__device__ __forceinline__ uint pack2(float lo, float hi) {
    return (uint)f2bf(lo) | ((uint)f2bf(hi) << 16);
}

// ------- fused weight-prep + degree count (padded counters, 1 edge/thread) --
__global__ __launch_bounds__(256) void k_prepdeg(const float* __restrict__ w1,
                                                 const float* __restrict__ w2,
                                                 const int* __restrict__ src,
                                                 const int* __restrict__ dst,
                                                 ushort* __restrict__ BtG,
                                                 float* __restrict__ bias,
                                                 int* __restrict__ out_deg,  // stride DPAD
                                                 int* __restrict__ in_deg,   // stride DPAD
                                                 ushort* __restrict__ rank) {
    int g = blockIdx.x * 256 + threadIdx.x;
    if (g < NCOMB * IN_F) {
        int n = g >> 8;
        int k = g & 255;
        float v = (n < OUT_F) ? w1[k * OUT_F + n] : w2[k * RANK + (n - OUT_F)];
        BtG[n * IN_F + k] = f2bf(v);
    }
    if (g < RANK) bias[g] = w2[IN_F * RANK + g];
    if (g < N_EDGES) {
        int s = src[g];
        int d = dst[g];
        atomicAdd(&out_deg[s << 3], 1);
        rank[g] = (ushort)atomicAdd(&in_deg[d << 3], 1);
    }
}

// ------- scan phase 1: per-block sums (padded in_deg) -------
__global__ __launch_bounds__(256) void k_bsum(const int* __restrict__ in_deg,
                                              int* __restrict__ bsum) {
    __shared__ int red[4];
    int t = threadIdx.x;
    int idx = blockIdx.x * 256 + t;
    int v = (idx < N_NODES) ? in_deg[idx << 3] : 0;
#pragma unroll
    for (int m = 1; m < 64; m <<= 1) v += __shfl_xor(v, m, 64);
    if ((t & 63) == 0) red[t >> 6] = v;
    __syncthreads();
    if (t == 0) bsum[blockIdx.x] = red[0] + red[1] + red[2] + red[3];
}

// ------- scan phase 2: tiny bsum scan + local scan -------
__global__ __launch_bounds__(256) void k_scat2(const int* __restrict__ in_deg,
                                               const int* __restrict__ bsum,
                                               int* __restrict__ row_start) {
    __shared__ int s[256];
    int t = threadIdx.x;
    int b = blockIdx.x;
    int bv = (t < NB_SCAN) ? bsum[t] : 0;
    s[t] = bv;
    __syncthreads();
    for (int st = 1; st < 256; st <<= 1) {
        int x = 0;
        if (t >= st) x = s[t - st];
        __syncthreads();
        if (t >= st) s[t] += x;
        __syncthreads();
    }
    int off = (b > 0) ? s[b - 1] : 0;
    __syncthreads();
    int idx = b * 256 + t;
    int v = (idx < N_NODES) ? in_deg[idx << 3] : 0;
    s[t] = v;
    __syncthreads();
    for (int st = 1; st < 256; st <<= 1) {
        int x = 0;
        if (t >= st) x = s[t - st];
        __syncthreads();
        if (t >= st) s[t] += x;
        __syncthreads();
    }
    if (idx < N_NODES) row_start[idx] = off + s[t] - v;
    if (b == NB_SCAN - 1 && t == 0) row_start[N_NODES] = N_EDGES;
}

// ------- fused MFMA node GEMM + atomic-free CSR fill (1:1 interleave) -----
#define BM 64
#define BK 64
__global__ __launch_bounds__(256) void k_gemmfill(
    const float* __restrict__ feat,
    const ushort* __restrict__ BtG,
    const float* __restrict__ bias,
    const int* __restrict__ out_deg,  // stride DPAD
    const int* __restrict__ src,
    const int* __restrict__ dst,
    const ushort* __restrict__ rank,
    const int* __restrict__ row_start,
    int* __restrict__ csr_src,
    ushort* __restrict__ feat_rec) {
    __shared__ __align__(16) ushort A_l[BM * BK];
    __shared__ __align__(16) ushort B_l[NCOMB * BK];
    int bid = blockIdx.x;
    int tid = threadIdx.x;

    if (bid & 1) {
        // fill block: 1024 edges, vectorized index reads, no atomics
        int base = (bid >> 1) * 1024 + tid * 4;
        if (base < N_EDGES) {
            int4 s4 = *(const int4*)(src + base);
            int4 d4 = *(const int4*)(dst + base);
            uint2 rq = *(const uint2*)(rank + base);
            csr_src[row_start[d4.x] + (int)(rq.x & 0xffff)] = s4.x;
            csr_src[row_start[d4.y] + (int)(rq.x >> 16)] = s4.y;
            csr_src[row_start[d4.z] + (int)(rq.y & 0xffff)] = s4.z;
            csr_src[row_start[d4.w] + (int)(rq.y >> 16)] = s4.w;
        }
        return;
    }

    int gid = bid >> 1;
    int wid = tid >> 6, lane = tid & 63;
    int n0 = gid * BM;

    f32x4 acc[12];
#pragma unroll
    for (int t = 0; t < 12; ++t) acc[t] = (f32x4)(0.f);

    int ar = tid >> 2;
    int ac = (tid & 3) << 4;
    const float* arow = feat + (size_t)(n0 + ar) * IN_F + ac;
    bool arow_ok = (n0 + ar) < N_NODES;

    float4 v0, v1, v2, v3;
    uint4 bg0, bg1, bg2, bg3, bg4, bg5;

#define LOADA(KT)                                                     \
    do {                                                              \
        if (arow_ok) {                                                \
            const float4* p = (const float4*)(arow + (KT) * BK);      \
            v0 = p[0]; v1 = p[1]; v2 = p[2]; v3 = p[3];               \
        } else {                                                      \
            v0 = v1 = v2 = v3 = make_float4(0.f, 0.f, 0.f, 0.f);     \
        }                                                             \
    } while (0)

#define LOADB1(II, DEST)                                              \
    do {                                                              \
        int cc = tid + 256 * (II);                                    \
        int row = cc >> 3;                                            \
        int cb = (cc & 7) << 4;                                       \
        DEST = *(const uint4*)((const char*)BtG + row * 512 + ktn * 128 + cb); \
    } while (0)

    {
        int ktn = 0;
        LOADA(0);
        LOADB1(0, bg0); LOADB1(1, bg1); LOADB1(2, bg2);
        LOADB1(3, bg3); LOADB1(4, bg4); LOADB1(5, bg5);
    }

    for (int kt = 0; kt < 4; ++kt) {
        {
            uint4 w0 = make_uint4(pack2(v0.x, v0.y), pack2(v0.z, v0.w),
                                  pack2(v1.x, v1.y), pack2(v1.z, v1.w));
            uint4 w1q = make_uint4(pack2(v2.x, v2.y), pack2(v2.z, v2.w),
                                   pack2(v3.x, v3.y), pack2(v3.z, v3.w));
            int base = ar * 128 + ac * 2;
            int swz = (ar & 7) << 4;
            *(uint4*)((char*)A_l + (base ^ swz)) = w0;
            *(uint4*)((char*)A_l + ((base + 16) ^ swz)) = w1q;
        }
        {
            uint4 bgs[6] = {bg0, bg1, bg2, bg3, bg4, bg5};
#pragma unroll
            for (int ii = 0; ii < 6; ++ii) {
                int cc = tid + 256 * ii;
                int row = cc >> 3;
                int cb = (cc & 7) << 4;
                int b = (row * 128 + cb) ^ ((row & 7) << 4);
                *(uint4*)((char*)B_l + b) = bgs[ii];
            }
        }
        __syncthreads();
        if (kt < 3) {
            int ktn = kt + 1;
            LOADA(ktn);
            LOADB1(0, bg0); LOADB1(1, bg1); LOADB1(2, bg2);
            LOADB1(3, bg3); LOADB1(4, bg4); LOADB1(5, bg5);
        }
        {
            int arow_f = wid * 16 + (lane & 15);
            int kchunk = lane >> 4;
            int aswz = (arow_f & 7) << 4;
#pragma unroll
            for (int s = 0; s < 2; ++s) {
                int abyte = (arow_f * 128 + s * 64 + kchunk * 16) ^ aswz;
                short8 afrag = *(const short8*)((const char*)A_l + abyte);
#pragma unroll
                for (int t = 0; t < 12; ++t) {
                    int brow = t * 16 + (lane & 15);
                    int bbyte = (brow * 128 + s * 64 + kchunk * 16) ^ ((brow & 7) << 4);
                    short8 bfrag = *(const short8*)((const char*)B_l + bbyte);
                    acc[t] = __builtin_amdgcn_mfma_f32_16x16x32_bf16(afrag, bfrag,
                                                                     acc[t], 0, 0, 0);
                }
            }
        }
        __syncthreads();
    }

    int col = lane & 15;
    int r0 = wid * 16 + ((lane >> 4) << 2);
#pragma unroll
    for (int q = 0; q < 4; ++q) {
        int n = n0 + r0 + q;
        if (n < N_NODES) {
            float s = rsqrtf(fmaxf((float)out_deg[n << 3], 1.f));
            ushort* rec = feat_rec + (size_t)n * REC;
#pragma unroll
            for (int t = 0; t < 8; ++t)
                rec[t * 16 + col] = f2bf(acc[t][q] * s);
#pragma unroll
            for (int t = 8; t < 12; ++t) {
                float z = acc[t][q] * s + bias[(t - 8) * 16 + col];
                rec[OUT_F + (t - 8) * 16 + col] = f2bf(tanhf(z));
            }
        }
    }
}

// ---------------- aggregation: unified 384-B record gather ----------------
__global__ __launch_bounds__(256) void k_agg(const ushort* __restrict__ feat_rec,
                                             const int* __restrict__ row_start,
                                             const int* __restrict__ csr_src,
                                             const int* __restrict__ in_deg,  // stride DPAD
                                             const float* __restrict__ vmat,
                                             float* __restrict__ out) {
    __shared__ float sum_s[4][OUT_F];
    __shared__ float prod_s[4][RANK];
    int wid = threadIdx.x >> 6;
    int lane = threadIdx.x & 63;
    int g = lane >> 4;
    int i = lane & 15;
    int d = blockIdx.x * 4 + wid;

    int beg = row_start[d];
    int end = row_start[d + 1];
    int deg = end - beg;

    const char* frb = (const char*)feat_rec;  // record stride 384 B

    float a0 = 0.f, a1 = 0.f, a2 = 0.f, a3 = 0.f;
    float a4 = 0.f, a5 = 0.f, a6 = 0.f, a7 = 0.f;
    float p0 = 1.f, p1 = 1.f, p2 = 1.f, p3 = 1.f;

    if (deg > 0) {
        int cl = end - 1;
        int e0 = beg + g * 4;
        int sA = csr_src[min(e0 + 0, cl)];
        int sB = csr_src[min(e0 + 1, cl)];
        int sC = csr_src[min(e0 + 2, cl)];
        int sD = csr_src[min(e0 + 3, cl)];
        int niter = (deg + 15) >> 4;
        for (int it = 0; it < niter; ++it) {
            size_t bA = (size_t)sA * 384, bB = (size_t)sB * 384;
            size_t bC = (size_t)sC * 384, bD = (size_t)sD * 384;
            uint4 uA = *(const uint4*)(frb + bA + (i << 4));
            uint4 uB = *(const uint4*)(frb + bB + (i << 4));
            uint4 uC = *(const uint4*)(frb + bC + (i << 4));
            uint4 uD = *(const uint4*)(frb + bD + (i << 4));
            uint2 qA = *(const uint2*)(frb + bA + 256 + (i << 3));
            uint2 qB = *(const uint2*)(frb + bB + 256 + (i << 3));
            uint2 qC = *(const uint2*)(frb + bC + 256 + (i << 3));
            uint2 qD = *(const uint2*)(frb + bD + 256 + (i << 3));
            bool vA = (e0 + 0) < end;
            bool vB = (e0 + 1) < end;
            bool vC = (e0 + 2) < end;
            bool vD = (e0 + 3) < end;
            float mA = vA ? 1.f : 0.f;
            float mB = vB ? 1.f : 0.f;
            float mC = vC ? 1.f : 0.f;
            float mD = vD ? 1.f : 0.f;
            e0 += 16;
            sA = csr_src[min(e0 + 0, cl)];
            sB = csr_src[min(e0 + 1, cl)];
            sC = csr_src[min(e0 + 2, cl)];
            sD = csr_src[min(e0 + 3, cl)];
            a0 = fmaf(mA, bflo(uA.x), a0); a1 = fmaf(mA, bfhi(uA.x), a1);
            a2 = fmaf(mA, bflo(uA.y), a2); a3 = fmaf(mA, bfhi(uA.y), a3);
            a4 = fmaf(mA, bflo(uA.z), a4); a5 = fmaf(mA, bfhi(uA.z), a5);
            a6 = fmaf(mA, bflo(uA.w), a6); a7 = fmaf(mA, bfhi(uA.w), a7);
            a0 = fmaf(mB, bflo(uB.x), a0); a1 = fmaf(mB, bfhi(uB.x), a1);
            a2 = fmaf(mB, bflo(uB.y), a2); a3 = fmaf(mB, bfhi(uB.y), a3);
            a4 = fmaf(mB, bflo(uB.z), a4); a5 = fmaf(mB, bfhi(uB.z), a5);
            a6 = fmaf(mB, bflo(uB.w), a6); a7 = fmaf(mB, bfhi(uB.w), a7);
            a0 = fmaf(mC, bflo(uC.x), a0); a1 = fmaf(mC, bfhi(uC.x), a1);
            a2 = fmaf(mC, bflo(uC.y), a2); a3 = fmaf(mC, bfhi(uC.y), a3);
            a4 = fmaf(mC, bflo(uC.z), a4); a5 = fmaf(mC, bfhi(uC.z), a5);
            a6 = fmaf(mC, bflo(uC.w), a6); a7 = fmaf(mC, bfhi(uC.w), a7);
            a0 = fmaf(mD, bflo(uD.x), a0); a1 = fmaf(mD, bfhi(uD.x), a1);
            a2 = fmaf(mD, bflo(uD.y), a2); a3 = fmaf(mD, bfhi(uD.y), a3);
            a4 = fmaf(mD, bflo(uD.z), a4); a5 = fmaf(mD, bfhi(uD.z), a5);
            a6 = fmaf(mD, bflo(uD.w), a6); a7 = fmaf(mD, bfhi(uD.w), a7);
            p0 *= vA ? bflo(qA.x) : 1.f; p1 *= vA ? bfhi(qA.x) : 1.f;
            p2 *= vA ? bflo(qA.y) : 1.f; p3 *= vA ? bfhi(qA.y) : 1.f;
            p0 *= vB ? bflo(qB.x) : 1.f; p1 *= vB ? bfhi(qB.x) : 1.f;
            p2 *= vB ? bflo(qB.y) : 1.f; p3 *= vB ? bfhi(qB.y) : 1.f;
            p0 *= vC ? bflo(qC.x) : 1.f; p1 *= vC ? bfhi(qC.x) : 1.f;
            p2 *= vC ? bflo(qC.y) : 1.f; p3 *= vC ? bfhi(qC.y) : 1.f;
            p0 *= vD ? bflo(qD.x) : 1.f; p1 *= vD ? bfhi(qD.x) : 1.f;
            p2 *= vD ? bflo(qD.y) : 1.f; p3 *= vD ? bfhi(qD.y) : 1.f;
        }
    }

    a0 += __shfl_xor(a0, 16, 64); a0 += __shfl_xor(a0, 32, 64);
    a1 += __shfl_xor(a1, 16, 64); a1 += __shfl_xor(a1, 32, 64);
    a2 += __shfl_xor(a2, 16, 64); a2 += __shfl_xor(a2, 32, 64);
    a3 += __shfl_xor(a3, 16, 64); a3 += __shfl_xor(a3, 32, 64);
    a4 += __shfl_xor(a4, 16, 64); a4 += __shfl_xor(a4, 32, 64);
    a5 += __shfl_xor(a5, 16, 64); a5 += __shfl_xor(a5, 32, 64);
    a6 += __shfl_xor(a6, 16, 64); a6 += __shfl_xor(a6, 32, 64);
    a7 += __shfl_xor(a7, 16, 64); a7 += __shfl_xor(a7, 32, 64);
    p0 *= __shfl_xor(p0, 16, 64); p0 *= __shfl_xor(p0, 32, 64);
    p1 *= __shfl_xor(p1, 16, 64); p1 *= __shfl_xor(p1, 32, 64);
    p2 *= __shfl_xor(p2, 16, 64); p2 *= __shfl_xor(p2, 32, 64);
    p3 *= __shfl_xor(p3, 16, 64); p3 *= __shfl_xor(p3, 32, 64);

    if (g == 0) {
        sum_s[wid][i * 8 + 0] = a0; sum_s[wid][i * 8 + 1] = a1;
        sum_s[wid][i * 8 + 2] = a2; sum_s[wid][i * 8 + 3] = a3;
        sum_s[wid][i * 8 + 4] = a4; sum_s[wid][i * 8 + 5] = a5;
        sum_s[wid][i * 8 + 6] = a6; sum_s[wid][i * 8 + 7] = a7;
        prod_s[wid][i * 4 + 0] = p0; prod_s[wid][i * 4 + 1] = p1;
        prod_s[wid][i * 4 + 2] = p2; prod_s[wid][i * 4 + 3] = p3;
    }

    float o0 = sum_s[wid][lane * 2];
    float o1 = sum_s[wid][lane * 2 + 1];
    if (deg > 0) {
#pragma unroll 8
        for (int r = 0; r < RANK; ++r) {
            float p = prod_s[wid][r];
            float2 v2 = *(const float2*)(vmat + r * OUT_F + lane * 2);
            o0 += p * v2.x;
            o1 += p * v2.y;
        }
    }
    float sc = rsqrtf(fmaxf((float)deg, 1.f));
    float2 res;
    res.x = o0 * sc;
    res.y = o1 * sc;
    *(float2*)(out + (size_t)d * OUT_F + lane * 2) = res;
}

extern "C" void kernel_launch(void* const* d_in, const int* in_sizes, int n_in,
                              void* d_out, int out_size, void* d_ws, size_t ws_size,
                              hipStream_t stream) {
    const float* feat = (const float*)d_in[0];
    const float* w1   = (const float*)d_in[1];
    const float* w2   = (const float*)d_in[2];
    const float* vmat = (const float*)d_in[3];
    const int*   src  = (const int*)d_in[4];
    const int*   dst  = (const int*)d_in[5];
    float* out = (float*)d_out;

    char* ws = (char*)d_ws;
    size_t off = 0;
    auto alloc = [&](size_t bytes) {
        void* p = ws + off;
        off = (off + bytes + 255) & ~(size_t)255;
        return p;
    };
    // padded degree arrays: one int per 32-B sector
    int* degs      = (int*)alloc(2 * N_NODES * DPAD * sizeof(int));
    int* out_deg   = degs;
    int* in_deg    = degs + N_NODES * DPAD;
    int* row_start = (int*)alloc((N_NODES + 1) * sizeof(int));
    int* csr_src   = (int*)alloc(N_EDGES * sizeof(int));
    int* bsum      = (int*)alloc(NB_SCAN * sizeof(int));
    ushort* rank   = (ushort*)alloc(N_EDGES * sizeof(ushort));
    ushort* feat_rec = (ushort*)alloc((size_t)N_NODES * REC * sizeof(ushort));
    ushort* BtG      = (ushort*)alloc((size_t)NCOMB * IN_F * sizeof(ushort));
    float*  bias     = (float*)alloc(RANK * sizeof(float));

    hipMemsetAsync(degs, 0, 2 * N_NODES * DPAD * sizeof(int), stream);

    k_prepdeg<<<(N_EDGES + 255) / 256, 256, 0, stream>>>(w1, w2, src, dst,
                                                         BtG, bias, out_deg,
                                                         in_deg, rank);
    k_bsum<<<NB_SCAN, 256, 0, stream>>>(in_deg, bsum);
    k_scat2<<<NB_SCAN, 256, 0, stream>>>(in_deg, bsum, row_start);
    k_gemmfill<<<NB_GEMM * 2, 256, 0, stream>>>(feat, BtG, bias, out_deg,
                                                src, dst, rank, row_start,
                                                csr_src, feat_rec);
    k_agg<<<N_NODES / 4, 256, 0, stream>>>(feat_rec, row_start, csr_src,
                                           in_deg, vmat, out);
}

// Round 12
// 178.820 us; speedup vs baseline: 1.4497x; 1.3290x over previous
//
#include <hip/hip_runtime.h>
#include <math.h>

#define N_NODES 50000
#define N_EDGES 800000
#define IN_F 256
#define OUT_F 128
#define RANK 64
#define NCOMB 192   // OUT_F + RANK
#define REC 192     // ushorts per node record (128 sum + 64 prod) = 384 B
#define NB_SCAN ((N_NODES + 255) / 256)  // 196
#define NB_GEMM ((N_NODES + 63) / 64)    // 782
#define NB_H 64                          // histogram chunks per direction
#define CHUNK (N_EDGES / NB_H)           // 12500 edges per chunk
#define HWORDS ((N_NODES + 1) / 2)       // 25000 packed uint words

typedef unsigned int uint;
typedef unsigned short ushort;
using f32x4 = __attribute__((ext_vector_type(4))) float;
typedef __attribute__((ext_vector_type(8))) short short8;

__device__ __forceinline__ ushort f2bf(float x) {
    uint u = __float_as_uint(x);
    uint r = (u + 0x7fffu + ((u >> 16) & 1u)) >> 16;
    return (ushort)r;
}
__device__ __forceinline__ float bflo(uint u) { return __uint_as_float(u << 16); }
__device__ __forceinline__ float bfhi(uint u) { return __uint_as_float(u & 0xffff0000u); }
__device__ __forceinline__ uint pack2(float lo, float hi) {
    return (uint)f2bf(lo) | ((uint)f2bf(hi) << 16);
}

// ------- LDS-histogram degree/rank build + weight prep (NO global atomics) --
// blocks 0..NB_H-1: dst-chunks (emit lrank); blocks NB_H..2*NB_H-1: src-chunks.
__global__ __launch_bounds__(256) void k_hist(const float* __restrict__ w1,
                                              const float* __restrict__ w2,
                                              const int* __restrict__ src,
                                              const int* __restrict__ dst,
                                              ushort* __restrict__ BtG,
                                              float* __restrict__ bias,
                                              uint* __restrict__ PIN,
                                              uint* __restrict__ POUT,
                                              ushort* __restrict__ lrank) {
    __shared__ uint hist[HWORDS];  // 100 KB: 2 ushort counters per word
    int b = blockIdx.x;
    int t = threadIdx.x;
    int g = b * 256 + t;

    // weight prep spread across all threads (2 elems max each)
    for (int i = g; i < NCOMB * IN_F; i += 2 * NB_H * 256) {
        int n = i >> 8;
        int k = i & 255;
        float v = (n < OUT_F) ? w1[k * OUT_F + n] : w2[k * RANK + (n - OUT_F)];
        BtG[n * IN_F + k] = f2bf(v);
    }
    if (g < RANK) bias[g] = w2[IN_F * RANK + g];

    for (int w = t; w < HWORDS; w += 256) hist[w] = 0;
    __syncthreads();

    if (b < NB_H) {
        // dst chunk with ranks
        int e0 = b * CHUNK;
        for (int i = t; i < CHUNK / 4; i += 256) {
            int e = e0 + i * 4;
            int4 d4 = *(const int4*)(dst + e);
            uint o0 = atomicAdd(&hist[d4.x >> 1], 1u << ((d4.x & 1) * 16));
            uint o1 = atomicAdd(&hist[d4.y >> 1], 1u << ((d4.y & 1) * 16));
            uint o2 = atomicAdd(&hist[d4.z >> 1], 1u << ((d4.z & 1) * 16));
            uint o3 = atomicAdd(&hist[d4.w >> 1], 1u << ((d4.w & 1) * 16));
            uint r0 = (o0 >> ((d4.x & 1) * 16)) & 0xffffu;
            uint r1 = (o1 >> ((d4.y & 1) * 16)) & 0xffffu;
            uint r2 = (o2 >> ((d4.z & 1) * 16)) & 0xffffu;
            uint r3 = (o3 >> ((d4.w & 1) * 16)) & 0xffffu;
            uint2 pk;
            pk.x = r0 | (r1 << 16);
            pk.y = r2 | (r3 << 16);
            *(uint2*)(lrank + e) = pk;
        }
        __syncthreads();
        for (int w = t; w < HWORDS; w += 256)
            PIN[(size_t)b * HWORDS + w] = hist[w];
    } else {
        // src chunk, totals only
        int c = b - NB_H;
        int e0 = c * CHUNK;
        for (int i = t; i < CHUNK / 4; i += 256) {
            int e = e0 + i * 4;
            int4 s4 = *(const int4*)(src + e);
            atomicAdd(&hist[s4.x >> 1], 1u << ((s4.x & 1) * 16));
            atomicAdd(&hist[s4.y >> 1], 1u << ((s4.y & 1) * 16));
            atomicAdd(&hist[s4.z >> 1], 1u << ((s4.z & 1) * 16));
            atomicAdd(&hist[s4.w >> 1], 1u << ((s4.w & 1) * 16));
        }
        __syncthreads();
        for (int w = t; w < HWORDS; w += 256)
            POUT[(size_t)c * HWORDS + w] = hist[w];
    }
}

// ------- per-node chunk-prefix scan + degree totals ----------------------
__global__ __launch_bounds__(256) void k_nodescan(const uint* __restrict__ PIN,
                                                  const uint* __restrict__ POUT,
                                                  uint* __restrict__ BPRE,
                                                  int* __restrict__ in_deg,
                                                  int* __restrict__ out_deg) {
    int w = blockIdx.x * 256 + threadIdx.x;
    if (w >= HWORDS) return;
    uint rl = 0, rh = 0;
    for (int b = 0; b < NB_H; ++b) {
        uint v = PIN[(size_t)b * HWORDS + w];
        BPRE[(size_t)b * HWORDS + w] = rl | (rh << 16);
        rl += v & 0xffffu;
        rh += v >> 16;
    }
    in_deg[2 * w] = (int)rl;
    in_deg[2 * w + 1] = (int)rh;
    uint sl = 0, sh = 0;
    for (int b = 0; b < NB_H; ++b) {
        uint v = POUT[(size_t)b * HWORDS + w];
        sl += v & 0xffffu;
        sh += v >> 16;
    }
    out_deg[2 * w] = (int)sl;
    out_deg[2 * w + 1] = (int)sh;
}

// ------- scan phase 1: per-block sums -------
__global__ __launch_bounds__(256) void k_bsum(const int* __restrict__ in_deg,
                                              int* __restrict__ bsum) {
    __shared__ int red[4];
    int t = threadIdx.x;
    int idx = blockIdx.x * 256 + t;
    int v = (idx < N_NODES) ? in_deg[idx] : 0;
#pragma unroll
    for (int m = 1; m < 64; m <<= 1) v += __shfl_xor(v, m, 64);
    if ((t & 63) == 0) red[t >> 6] = v;
    __syncthreads();
    if (t == 0) bsum[blockIdx.x] = red[0] + red[1] + red[2] + red[3];
}

// ------- scan phase 2: tiny bsum scan + local scan -------
__global__ __launch_bounds__(256) void k_scat2(const int* __restrict__ in_deg,
                                               const int* __restrict__ bsum,
                                               int* __restrict__ row_start) {
    __shared__ int s[256];
    int t = threadIdx.x;
    int b = blockIdx.x;
    int bv = (t < NB_SCAN) ? bsum[t] : 0;
    s[t] = bv;
    __syncthreads();
    for (int st = 1; st < 256; st <<= 1) {
        int x = 0;
        if (t >= st) x = s[t - st];
        __syncthreads();
        if (t >= st) s[t] += x;
        __syncthreads();
    }
    int off = (b > 0) ? s[b - 1] : 0;
    __syncthreads();
    int idx = b * 256 + t;
    int v = (idx < N_NODES) ? in_deg[idx] : 0;
    s[t] = v;
    __syncthreads();
    for (int st = 1; st < 256; st <<= 1) {
        int x = 0;
        if (t >= st) x = s[t - st];
        __syncthreads();
        if (t >= st) s[t] += x;
        __syncthreads();
    }
    if (idx < N_NODES) row_start[idx] = off + s[t] - v;
    if (b == NB_SCAN - 1 && t == 0) row_start[N_NODES] = N_EDGES;
}

// ------- fused MFMA node GEMM + atomic-free CSR fill (1:1 interleave) -----
#define BM 64
#define BK 64
__global__ __launch_bounds__(256) void k_gemmfill(
    const float* __restrict__ feat,
    const ushort* __restrict__ BtG,
    const float* __restrict__ bias,
    const int* __restrict__ out_deg,
    const int* __restrict__ src,
    const int* __restrict__ dst,
    const ushort* __restrict__ lrank,
    const uint* __restrict__ BPRE,
    const int* __restrict__ row_start,
    int* __restrict__ csr_src,
    ushort* __restrict__ feat_rec) {
    __shared__ __align__(16) ushort A_l[BM * BK];
    __shared__ __align__(16) ushort B_l[NCOMB * BK];
    int bid = blockIdx.x;
    int tid = threadIdx.x;

    if (bid & 1) {
        // fill block: 1024 edges; p = row_start + chunk-prefix + local-rank
        int base = (bid >> 1) * 1024 + tid * 4;
        if (base < N_EDGES) {
            int c = base / CHUNK;  // all 4 edges share the chunk (CHUNK%4==0)
            const uint* bp = BPRE + (size_t)c * HWORDS;
            int4 s4 = *(const int4*)(src + base);
            int4 d4 = *(const int4*)(dst + base);
            uint2 rq = *(const uint2*)(lrank + base);
            int p0 = row_start[d4.x] +
                     (int)((bp[d4.x >> 1] >> ((d4.x & 1) * 16)) & 0xffffu) +
                     (int)(rq.x & 0xffffu);
            int p1 = row_start[d4.y] +
                     (int)((bp[d4.y >> 1] >> ((d4.y & 1) * 16)) & 0xffffu) +
                     (int)(rq.x >> 16);
            int p2 = row_start[d4.z] +
                     (int)((bp[d4.z >> 1] >> ((d4.z & 1) * 16)) & 0xffffu) +
                     (int)(rq.y & 0xffffu);
            int p3 = row_start[d4.w] +
                     (int)((bp[d4.w >> 1] >> ((d4.w & 1) * 16)) & 0xffffu) +
                     (int)(rq.y >> 16);
            csr_src[p0] = s4.x;
            csr_src[p1] = s4.y;
            csr_src[p2] = s4.z;
            csr_src[p3] = s4.w;
        }
        return;
    }

    int gid = bid >> 1;
    int wid = tid >> 6, lane = tid & 63;
    int n0 = gid * BM;

    f32x4 acc[12];
#pragma unroll
    for (int t = 0; t < 12; ++t) acc[t] = (f32x4)(0.f);

    int ar = tid >> 2;
    int ac = (tid & 3) << 4;
    const float* arow = feat + (size_t)(n0 + ar) * IN_F + ac;
    bool arow_ok = (n0 + ar) < N_NODES;

    float4 v0, v1, v2, v3;
    uint4 bg0, bg1, bg2, bg3, bg4, bg5;

#define LOADA(KT)                                                     \
    do {                                                              \
        if (arow_ok) {                                                \
            const float4* p = (const float4*)(arow + (KT) * BK);      \
            v0 = p[0]; v1 = p[1]; v2 = p[2]; v3 = p[3];               \
        } else {                                                      \
            v0 = v1 = v2 = v3 = make_float4(0.f, 0.f, 0.f, 0.f);     \
        }                                                             \
    } while (0)

#define LOADB1(II, DEST)                                              \
    do {                                                              \
        int cc = tid + 256 * (II);                                    \
        int row = cc >> 3;                                            \
        int cb = (cc & 7) << 4;                                       \
        DEST = *(const uint4*)((const char*)BtG + row * 512 + ktn * 128 + cb); \
    } while (0)

    {
        int ktn = 0;
        LOADA(0);
        LOADB1(0, bg0); LOADB1(1, bg1); LOADB1(2, bg2);
        LOADB1(3, bg3); LOADB1(4, bg4); LOADB1(5, bg5);
    }

    for (int kt = 0; kt < 4; ++kt) {
        {
            uint4 w0 = make_uint4(pack2(v0.x, v0.y), pack2(v0.z, v0.w),
                                  pack2(v1.x, v1.y), pack2(v1.z, v1.w));
            uint4 w1q = make_uint4(pack2(v2.x, v2.y), pack2(v2.z, v2.w),
                                   pack2(v3.x, v3.y), pack2(v3.z, v3.w));
            int base = ar * 128 + ac * 2;
            int swz = (ar & 7) << 4;
            *(uint4*)((char*)A_l + (base ^ swz)) = w0;
            *(uint4*)((char*)A_l + ((base + 16) ^ swz)) = w1q;
        }
        {
            uint4 bgs[6] = {bg0, bg1, bg2, bg3, bg4, bg5};
#pragma unroll
            for (int ii = 0; ii < 6; ++ii) {
                int cc = tid + 256 * ii;
                int row = cc >> 3;
                int cb = (cc & 7) << 4;
                int b = (row * 128 + cb) ^ ((row & 7) << 4);
                *(uint4*)((char*)B_l + b) = bgs[ii];
            }
        }
        __syncthreads();
        if (kt < 3) {
            int ktn = kt + 1;
            LOADA(ktn);
            LOADB1(0, bg0); LOADB1(1, bg1); LOADB1(2, bg2);
            LOADB1(3, bg3); LOADB1(4, bg4); LOADB1(5, bg5);
        }
        {
            int arow_f = wid * 16 + (lane & 15);
            int kchunk = lane >> 4;
            int aswz = (arow_f & 7) << 4;
#pragma unroll
            for (int s = 0; s < 2; ++s) {
                int abyte = (arow_f * 128 + s * 64 + kchunk * 16) ^ aswz;
                short8 afrag = *(const short8*)((const char*)A_l + abyte);
#pragma unroll
                for (int t = 0; t < 12; ++t) {
                    int brow = t * 16 + (lane & 15);
                    int bbyte = (brow * 128 + s * 64 + kchunk * 16) ^ ((brow & 7) << 4);
                    short8 bfrag = *(const short8*)((const char*)B_l + bbyte);
                    acc[t] = __builtin_amdgcn_mfma_f32_16x16x32_bf16(afrag, bfrag,
                                                                     acc[t], 0, 0, 0);
                }
            }
        }
        __syncthreads();
    }

    int col = lane & 15;
    int r0 = wid * 16 + ((lane >> 4) << 2);
#pragma unroll
    for (int q = 0; q < 4; ++q) {
        int n = n0 + r0 + q;
        if (n < N_NODES) {
            float s = rsqrtf(fmaxf((float)out_deg[n], 1.f));
            ushort* rec = feat_rec + (size_t)n * REC;
#pragma unroll
            for (int t = 0; t < 8; ++t)
                rec[t * 16 + col] = f2bf(acc[t][q] * s);
#pragma unroll
            for (int t = 8; t < 12; ++t) {
                float z = acc[t][q] * s + bias[(t - 8) * 16 + col];
                rec[OUT_F + (t - 8) * 16 + col] = f2bf(tanhf(z));
            }
        }
    }
}

// ---------------- aggregation: unified 384-B record gather ----------------
__global__ __launch_bounds__(256) void k_agg(const ushort* __restrict__ feat_rec,
                                             const int* __restrict__ row_start,
                                             const int* __restrict__ csr_src,
                                             const float* __restrict__ vmat,
                                             float* __restrict__ out) {
    __shared__ float sum_s[4][OUT_F];
    __shared__ float prod_s[4][RANK];
    int wid = threadIdx.x >> 6;
    int lane = threadIdx.x & 63;
    int g = lane >> 4;
    int i = lane & 15;
    int d = blockIdx.x * 4 + wid;

    int beg = row_start[d];
    int end = row_start[d + 1];
    int deg = end - beg;

    const char* frb = (const char*)feat_rec;  // record stride 384 B

    float a0 = 0.f, a1 = 0.f, a2 = 0.f, a3 = 0.f;
    float a4 = 0.f, a5 = 0.f, a6 = 0.f, a7 = 0.f;
    float p0 = 1.f, p1 = 1.f, p2 = 1.f, p3 = 1.f;

    if (deg > 0) {
        int cl = end - 1;
        int e0 = beg + g * 4;
        int sA = csr_src[min(e0 + 0, cl)];
        int sB = csr_src[min(e0 + 1, cl)];
        int sC = csr_src[min(e0 + 2, cl)];
        int sD = csr_src[min(e0 + 3, cl)];
        int niter = (deg + 15) >> 4;
        for (int it = 0; it < niter; ++it) {
            size_t bA = (size_t)sA * 384, bB = (size_t)sB * 384;
            size_t bC = (size_t)sC * 384, bD = (size_t)sD * 384;
            uint4 uA = *(const uint4*)(frb + bA + (i << 4));
            uint4 uB = *(const uint4*)(frb + bB + (i << 4));
            uint4 uC = *(const uint4*)(frb + bC + (i << 4));
            uint4 uD = *(const uint4*)(frb + bD + (i << 4));
            uint2 qA = *(const uint2*)(frb + bA + 256 + (i << 3));
            uint2 qB = *(const uint2*)(frb + bB + 256 + (i << 3));
            uint2 qC = *(const uint2*)(frb + bC + 256 + (i << 3));
            uint2 qD = *(const uint2*)(frb + bD + 256 + (i << 3));
            bool vA = (e0 + 0) < end;
            bool vB = (e0 + 1) < end;
            bool vC = (e0 + 2) < end;
            bool vD = (e0 + 3) < end;
            float mA = vA ? 1.f : 0.f;
            float mB = vB ? 1.f : 0.f;
            float mC = vC ? 1.f : 0.f;
            float mD = vD ? 1.f : 0.f;
            e0 += 16;
            sA = csr_src[min(e0 + 0, cl)];
            sB = csr_src[min(e0 + 1, cl)];
            sC = csr_src[min(e0 + 2, cl)];
            sD = csr_src[min(e0 + 3, cl)];
            a0 = fmaf(mA, bflo(uA.x), a0); a1 = fmaf(mA, bfhi(uA.x), a1);
            a2 = fmaf(mA, bflo(uA.y), a2); a3 = fmaf(mA, bfhi(uA.y), a3);
            a4 = fmaf(mA, bflo(uA.z), a4); a5 = fmaf(mA, bfhi(uA.z), a5);
            a6 = fmaf(mA, bflo(uA.w), a6); a7 = fmaf(mA, bfhi(uA.w), a7);
            a0 = fmaf(mB, bflo(uB.x), a0); a1 = fmaf(mB, bfhi(uB.x), a1);
            a2 = fmaf(mB, bflo(uB.y), a2); a3 = fmaf(mB, bfhi(uB.y), a3);
            a4 = fmaf(mB, bflo(uB.z), a4); a5 = fmaf(mB, bfhi(uB.z), a5);
            a6 = fmaf(mB, bflo(uB.w), a6); a7 = fmaf(mB, bfhi(uB.w), a7);
            a0 = fmaf(mC, bflo(uC.x), a0); a1 = fmaf(mC, bfhi(uC.x), a1);
            a2 = fmaf(mC, bflo(uC.y), a2); a3 = fmaf(mC, bfhi(uC.y), a3);
            a4 = fmaf(mC, bflo(uC.z), a4); a5 = fmaf(mC, bfhi(uC.z), a5);
            a6 = fmaf(mC, bflo(uC.w), a6); a7 = fmaf(mC, bfhi(uC.w), a7);
            a0 = fmaf(mD, bflo(uD.x), a0); a1 = fmaf(mD, bfhi(uD.x), a1);
            a2 = fmaf(mD, bflo(uD.y), a2); a3 = fmaf(mD, bfhi(uD.y), a3);
            a4 = fmaf(mD, bflo(uD.z), a4); a5 = fmaf(mD, bfhi(uD.z), a5);
            a6 = fmaf(mD, bflo(uD.w), a6); a7 = fmaf(mD, bfhi(uD.w), a7);
            p0 *= vA ? bflo(qA.x) : 1.f; p1 *= vA ? bfhi(qA.x) : 1.f;
            p2 *= vA ? bflo(qA.y) : 1.f; p3 *= vA ? bfhi(qA.y) : 1.f;
            p0 *= vB ? bflo(qB.x) : 1.f; p1 *= vB ? bfhi(qB.x) : 1.f;
            p2 *= vB ? bflo(qB.y) : 1.f; p3 *= vB ? bfhi(qB.y) : 1.f;
            p0 *= vC ? bflo(qC.x) : 1.f; p1 *= vC ? bfhi(qC.x) : 1.f;
            p2 *= vC ? bflo(qC.y) : 1.f; p3 *= vC ? bfhi(qC.y) : 1.f;
            p0 *= vD ? bflo(qD.x) : 1.f; p1 *= vD ? bfhi(qD.x) : 1.f;
            p2 *= vD ? bflo(qD.y) : 1.f; p3 *= vD ? bfhi(qD.y) : 1.f;
        }
    }

    a0 += __shfl_xor(a0, 16, 64); a0 += __shfl_xor(a0, 32, 64);
    a1 += __shfl_xor(a1, 16, 64); a1 += __shfl_xor(a1, 32, 64);
    a2 += __shfl_xor(a2, 16, 64); a2 += __shfl_xor(a2, 32, 64);
    a3 += __shfl_xor(a3, 16, 64); a3 += __shfl_xor(a3, 32, 64);
    a4 += __shfl_xor(a4, 16, 64); a4 += __shfl_xor(a4, 32, 64);
    a5 += __shfl_xor(a5, 16, 64); a5 += __shfl_xor(a5, 32, 64);
    a6 += __shfl_xor(a6, 16, 64); a6 += __shfl_xor(a6, 32, 64);
    a7 += __shfl_xor(a7, 16, 64); a7 += __shfl_xor(a7, 32, 64);
    p0 *= __shfl_xor(p0, 16, 64); p0 *= __shfl_xor(p0, 32, 64);
    p1 *= __shfl_xor(p1, 16, 64); p1 *= __shfl_xor(p1, 32, 64);
    p2 *= __shfl_xor(p2, 16, 64); p2 *= __shfl_xor(p2, 32, 64);
    p3 *= __shfl_xor(p3, 16, 64); p3 *= __shfl_xor(p3, 32, 64);

    if (g == 0) {
        sum_s[wid][i * 8 + 0] = a0; sum_s[wid][i * 8 + 1] = a1;
        sum_s[wid][i * 8 + 2] = a2; sum_s[wid][i * 8 + 3] = a3;
        sum_s[wid][i * 8 + 4] = a4; sum_s[wid][i * 8 + 5] = a5;
        sum_s[wid][i * 8 + 6] = a6; sum_s[wid][i * 8 + 7] = a7;
        prod_s[wid][i * 4 + 0] = p0; prod_s[wid][i * 4 + 1] = p1;
        prod_s[wid][i * 4 + 2] = p2; prod_s[wid][i * 4 + 3] = p3;
    }

    float o0 = sum_s[wid][lane * 2];
    float o1 = sum_s[wid][lane * 2 + 1];
    if (deg > 0) {
#pragma unroll 8
        for (int r = 0; r < RANK; ++r) {
            float p = prod_s[wid][r];
            float2 v2 = *(const float2*)(vmat + r * OUT_F + lane * 2);
            o0 += p * v2.x;
            o1 += p * v2.y;
        }
    }
    float sc = rsqrtf(fmaxf((float)deg, 1.f));
    float2 res;
    res.x = o0 * sc;
    res.y = o1 * sc;
    *(float2*)(out + (size_t)d * OUT_F + lane * 2) = res;
}

extern "C" void kernel_launch(void* const* d_in, const int* in_sizes, int n_in,
                              void* d_out, int out_size, void* d_ws, size_t ws_size,
                              hipStream_t stream) {
    const float* feat = (const float*)d_in[0];
    const float* w1   = (const float*)d_in[1];
    const float* w2   = (const float*)d_in[2];
    const float* vmat = (const float*)d_in[3];
    const int*   src  = (const int*)d_in[4];
    const int*   dst  = (const int*)d_in[5];
    float* out = (float*)d_out;

    char* ws = (char*)d_ws;
    size_t off = 0;
    auto alloc = [&](size_t bytes) {
        void* p = ws + off;
        off = (off + bytes + 255) & ~(size_t)255;
        return p;
    };
    int* out_deg   = (int*)alloc(N_NODES * sizeof(int));
    int* in_deg    = (int*)alloc(N_NODES * sizeof(int));
    int* row_start = (int*)alloc((N_NODES + 1) * sizeof(int));
    int* csr_src   = (int*)alloc(N_EDGES * sizeof(int));
    int* bsum      = (int*)alloc(NB_SCAN * sizeof(int));
    uint* PIN      = (uint*)alloc((size_t)NB_H * HWORDS * sizeof(uint));   // 6.4 MB
    uint* POUT     = (uint*)alloc((size_t)NB_H * HWORDS * sizeof(uint));   // 6.4 MB
    uint* BPRE     = (uint*)alloc((size_t)NB_H * HWORDS * sizeof(uint));   // 6.4 MB
    ushort* lrank  = (ushort*)alloc(N_EDGES * sizeof(ushort));
    ushort* feat_rec = (ushort*)alloc((size_t)N_NODES * REC * sizeof(ushort));
    ushort* BtG      = (ushort*)alloc((size_t)NCOMB * IN_F * sizeof(ushort));
    float*  bias     = (float*)alloc(RANK * sizeof(float));

    k_hist<<<2 * NB_H, 256, 0, stream>>>(w1, w2, src, dst, BtG, bias,
                                         PIN, POUT, lrank);
    k_nodescan<<<(HWORDS + 255) / 256, 256, 0, stream>>>(PIN, POUT, BPRE,
                                                         in_deg, out_deg);
    k_bsum<<<NB_SCAN, 256, 0, stream>>>(in_deg, bsum);
    k_scat2<<<NB_SCAN, 256, 0, stream>>>(in_deg, bsum, row_start);
    k_gemmfill<<<NB_GEMM * 2, 256, 0, stream>>>(feat, BtG, bias, out_deg,
                                                src, dst, lrank, BPRE, row_start,
                                                csr_src, feat_rec);
    k_agg<<<N_NODES / 4, 256, 0, stream>>>(feat_rec, row_start, csr_src,
                                           vmat, out);
}